// Round 6
// baseline (473.312 us; speedup 1.0000x reference)
//
#include <hip/hip_runtime.h>
#include <float.h>

#define D    64
#define K    512
#define HW   4096      // 64*64
#define NPIX 131072    // 32*4096
#define KT   8

// ws layout:
// [0,    2048)          float ck[512]   (np-style sum(cb*cb, axis=0))
// [2048, 2048+4*NPIX)   int   idx[NPIX]

// c_k = np.sum(cb*cb, axis=0)[k]: outer-axis reduce -> SEQUENTIAL adds over d,
// each square rounded to f32 first. fp-contract off so e*e is not fused.
__global__ void vq_prep(const float* __restrict__ cb, float* __restrict__ ck) {
#pragma clang fp contract(off)
    const int k = threadIdx.x;
    float s = 0.f;
    for (int d = 0; d < D; ++d) {
        const float e  = cb[d * K + k];
        const float e2 = e * e;
        s = s + e2;
    }
    ck[k] = s;
}

// Split-K x4: block = 64 pixels, 4 waves; wave w scans codes [w*128,(w+1)*128).
// x staged in LDS. cb is loaded via VECTOR loads (vmcnt) -- the address is
// laundered through an opaque VGPR zero so the compiler cannot scalarize it.
// Round-5 lesson: s_load(cb) + ds_read(xs) share lgkmcnt (SMEM completes
// out-of-order) -> per-d full drains -> 65% VALUBusy. Splitting the counters
// (cb->vmcnt, xs->lgkmcnt in-order) lets both pipeline.
__global__ __launch_bounds__(256, 8) void vq_main(const float* __restrict__ enc,
        const float* __restrict__ cb, const float* __restrict__ ck,
        int* __restrict__ idx) {
    __shared__ float xs[D][64];     // 16 KB: xs[d][pix]
    __shared__ float bvs[3][64];
    __shared__ int   bis[3][64];

    const int t    = threadIdx.x;
    const int lane = t & 63;
    const int wu   = __builtin_amdgcn_readfirstlane(t >> 6);  // wave id 0..3

    const int base = blockIdx.x * 64;      // 64 pixels per block, same b
    const int b    = base >> 12;
    const int hw0  = base & 4095;
    const float* ep = enc + (size_t)b * (D * HW) + hw0;

    // stage x: 4096 floats, coalesced
    #pragma unroll
    for (int i = 0; i < 16; ++i) {
        const int id  = t + i * 256;
        const int d   = id >> 6;
        const int pix = id & 63;
        xs[d][pix] = ep[(size_t)d * HW + pix];
    }
    __syncthreads();

    // t1 = np.sum(flat*flat, axis=1): numpy pairwise, n=64 contiguous path:
    // 8 sequential accumulators then ((r0+r1)+(r2+r3))+((r4+r5)+(r6+r7)).
    // Squares pre-rounded, no fma fusing.
    float t1;
    {
#pragma clang fp contract(off)
        float r[8];
        #pragma unroll
        for (int j = 0; j < 8; ++j) {
            const float v = xs[j][lane];
            r[j] = v * v;
        }
        #pragma unroll
        for (int i = 8; i < 64; i += 8) {
            #pragma unroll
            for (int j = 0; j < 8; ++j) {
                const float v  = xs[i + j][lane];
                const float v2 = v * v;
                r[j] = r[j] + v2;
            }
        }
        t1 = ((r[0] + r[1]) + (r[2] + r[3])) + ((r[4] + r[5]) + (r[6] + r[7]));
    }

    // opaque zero in a VGPR: forces cb addresses divergent -> global_load (vmcnt)
    int zero;
    asm volatile("v_mov_b32 %0, 0" : "=v"(zero));

    float best = FLT_MAX;
    int besti = 0;
    const int kbase = wu * (K / 4);
    const char* cbb = (const char*)cb;
    #pragma unroll 1
    for (int k0 = 0; k0 < K / 4; k0 += KT) {
        // sgemm semantics: single sequential fma chain over d (ascending)
        float acc[KT];
        #pragma unroll
        for (int j = 0; j < KT; ++j) acc[j] = 0.f;
        int voff = ((kbase + k0) << 2) + zero;     // byte offset, divergent-typed
        #pragma unroll 4
        for (int d = 0; d < D; ++d) {
            const float xv = xs[d][lane];          // ds_read, conflict-free
            const float4 c0 = *(const float4*)(cbb + voff);        // global_load_dwordx4
            const float4 c1 = *(const float4*)(cbb + voff + 16);   // global_load_dwordx4
            voff += K * 4;
            acc[0] = fmaf(xv, c0.x, acc[0]);
            acc[1] = fmaf(xv, c0.y, acc[1]);
            acc[2] = fmaf(xv, c0.z, acc[2]);
            acc[3] = fmaf(xv, c0.w, acc[3]);
            acc[4] = fmaf(xv, c1.x, acc[4]);
            acc[5] = fmaf(xv, c1.y, acc[5]);
            acc[6] = fmaf(xv, c1.z, acc[6]);
            acc[7] = fmaf(xv, c1.w, acc[7]);
        }
        // dist = (t1 - 2*dot) + c.  fmaf(-2,acc,t1) rounds the exact
        // t1-2*acc once == numpy's sub of the exact product; then one add.
        #pragma unroll
        for (int j = 0; j < KT; ++j) {
            const float u    = fmaf(-2.0f, acc[j], t1);
            const float dist = u + ck[kbase + k0 + j];
            if (dist < best) { best = dist; besti = kbase + k0 + j; }  // strict <
        }
    }

    // combine quarters in ascending order; strict < keeps lowest k on ties
    if (wu > 0) { bvs[wu - 1][lane] = best; bis[wu - 1][lane] = besti; }
    __syncthreads();
    if (wu == 0) {
        #pragma unroll
        for (int q = 0; q < 3; ++q) {
            const float ov = bvs[q][lane];
            const int   oi = bis[q][lane];
            if (ov < best) { best = ov; besti = oi; }
        }
        idx[base + lane] = besti;
    }
}

// float4/int4 vectorized scatter of the winning codebook vectors
__global__ void vq_out(const float* __restrict__ cb, const int* __restrict__ idx,
                       float* __restrict__ out) {
    const int o = (blockIdx.x * 256 + threadIdx.x) * 4;
    const int d = (o >> 12) & 63;
    const int bhw = ((o >> 18) << 12) | (o & 4095);
    const int4 iv = *reinterpret_cast<const int4*>(idx + bhw);
    float4 v;
    v.x = cb[d * K + iv.x];
    v.y = cb[d * K + iv.y];
    v.z = cb[d * K + iv.z];
    v.w = cb[d * K + iv.w];
    *reinterpret_cast<float4*>(out + o) = v;
}

extern "C" void kernel_launch(void* const* d_in, const int* in_sizes, int n_in,
                              void* d_out, int out_size, void* d_ws, size_t ws_size,
                              hipStream_t stream) {
    const float* enc = (const float*)d_in[0];
    const float* cb  = (const float*)d_in[1];
    float* out = (float*)d_out;
    char* ws = (char*)d_ws;
    float* ck  = (float*)ws;
    int*   idx = (int*)(ws + 2048);

    vq_prep<<<1, K, 0, stream>>>(cb, ck);
    vq_main<<<NPIX / 64, 256, 0, stream>>>(enc, cb, ck, idx);
    vq_out<<<out_size / 1024, 256, 0, stream>>>(cb, idx, out);
}

// Round 7
// 128.273 us; speedup vs baseline: 3.6899x; 3.6899x over previous
//
#include <hip/hip_runtime.h>
#include <float.h>

#define D    64
#define K    512
#define HW   4096      // 64*64
#define NPIX 131072    // 32*4096
#define KT   16

// ws layout:
// [0,    2048)          float ck[512]   (np-style sum(cb*cb, axis=0))
// [2048, 2048+4*NPIX)   int   idx[NPIX]

// c_k = np.sum(cb*cb, axis=0)[k]: outer-axis reduce -> SEQUENTIAL adds over d,
// each square rounded to f32 first. fp-contract off so e*e is not fused.
__global__ void vq_prep(const float* __restrict__ cb, float* __restrict__ ck) {
#pragma clang fp contract(off)
    const int k = threadIdx.x;
    float s = 0.f;
    for (int d = 0; d < D; ++d) {
        const float e  = cb[d * K + k];
        const float e2 = e * e;
        s = s + e2;
    }
    ck[k] = s;
}

// Split-K x4: block = 64 pixels, 4 waves; wave w scans codes [w*128,(w+1)*128).
// x staged in LDS; cb rows wave-uniform -> s_load (round-6 lesson: vector loads
// of uniform addresses are 4x WORSE).  KT=16 keeps VGPR ~20 -> 8 waves/SIMD.
// NEW (round 7): per-wave/per-block TILE ROTATION desynchronizes the 8
// co-resident waves so their lgkmcnt(0) drains interleave (TLP covers SMEM
// latency) instead of phase-locking.  Rotation requires an explicit index
// tie-break in the running argmin to keep numpy first-occurrence semantics.
__global__ __launch_bounds__(256, 8) void vq_main(const float* __restrict__ enc,
        const float* __restrict__ cb, const float* __restrict__ ck,
        int* __restrict__ idx) {
    __shared__ float xs[D][64];     // 16 KB: xs[d][pix]
    __shared__ float bvs[3][64];
    __shared__ int   bis[3][64];

    const int t    = threadIdx.x;
    const int lane = t & 63;
    const int wu   = __builtin_amdgcn_readfirstlane(t >> 6);  // wave id 0..3

    const int base = blockIdx.x * 64;      // 64 pixels per block, same b
    const int b    = base >> 12;
    const int hw0  = base & 4095;
    const float* ep = enc + (size_t)b * (D * HW) + hw0;

    // stage x: 4096 floats, coalesced
    #pragma unroll
    for (int i = 0; i < 16; ++i) {
        const int id  = t + i * 256;
        const int d   = id >> 6;
        const int pix = id & 63;
        xs[d][pix] = ep[(size_t)d * HW + pix];
    }
    __syncthreads();

    // t1 = np.sum(flat*flat, axis=1): numpy pairwise, n=64 contiguous path:
    // 8 sequential accumulators then ((r0+r1)+(r2+r3))+((r4+r5)+(r6+r7)).
    // Squares pre-rounded, no fma fusing.
    float t1;
    {
#pragma clang fp contract(off)
        float r[8];
        #pragma unroll
        for (int j = 0; j < 8; ++j) {
            const float v = xs[j][lane];
            r[j] = v * v;
        }
        #pragma unroll
        for (int i = 8; i < 64; i += 8) {
            #pragma unroll
            for (int j = 0; j < 8; ++j) {
                const float v  = xs[i + j][lane];
                const float v2 = v * v;
                r[j] = r[j] + v2;
            }
        }
        t1 = ((r[0] + r[1]) + (r[2] + r[3])) + ((r[4] + r[5]) + (r[6] + r[7]));
    }

    float best = FLT_MAX;
    int besti  = 0x7fffffff;
    const int kbase = wu * (K / 4);
    // per-wave + per-block rotation phase (covers both consecutive and
    // strided co-resident block numbering)
    const int rot = __builtin_amdgcn_readfirstlane(
        (((int)blockIdx.x + ((int)blockIdx.x >> 8)) * 3 + wu * 2) & 7);
    #pragma unroll 1
    for (int tt = 0; tt < 8; ++tt) {
        const int k0 = kbase + (((tt + rot) & 7) * KT);
        // sgemm semantics: single sequential fma chain over d (ascending)
        float acc[KT];
        #pragma unroll
        for (int j = 0; j < KT; ++j) acc[j] = 0.f;
        #pragma unroll 8
        for (int d = 0; d < D; ++d) {
            const float xv = xs[d][lane];              // ds_read, conflict-free
            const float* cbrow = cb + d * K + k0;      // wave-uniform -> s_load
            #pragma unroll
            for (int j = 0; j < KT; ++j)
                acc[j] = fmaf(xv, cbrow[j], acc[j]);
        }
        // dist = (t1 - 2*dot) + c.  fmaf(-2,acc,t1) rounds the exact
        // t1-2*acc once == numpy's sub of the exact product; then one add.
        // Tie-break on equal value -> lower index (numpy first-occurrence),
        // required because tiles are visited out of order.
        #pragma unroll
        for (int j = 0; j < KT; ++j) {
            const float u    = fmaf(-2.0f, acc[j], t1);
            const float dist = u + ck[k0 + j];
            const int   ki   = k0 + j;
            if (dist < best || (dist == best && ki < besti)) {
                best = dist; besti = ki;
            }
        }
    }

    // combine quarters in ascending order; strict < keeps lowest k on ties
    if (wu > 0) { bvs[wu - 1][lane] = best; bis[wu - 1][lane] = besti; }
    __syncthreads();
    if (wu == 0) {
        #pragma unroll
        for (int q = 0; q < 3; ++q) {
            const float ov = bvs[q][lane];
            const int   oi = bis[q][lane];
            if (ov < best) { best = ov; besti = oi; }
        }
        idx[base + lane] = besti;
    }
}

// float4/int4 vectorized scatter of the winning codebook vectors
__global__ void vq_out(const float* __restrict__ cb, const int* __restrict__ idx,
                       float* __restrict__ out) {
    const int o = (blockIdx.x * 256 + threadIdx.x) * 4;
    const int d = (o >> 12) & 63;
    const int bhw = ((o >> 18) << 12) | (o & 4095);
    const int4 iv = *reinterpret_cast<const int4*>(idx + bhw);
    float4 v;
    v.x = cb[d * K + iv.x];
    v.y = cb[d * K + iv.y];
    v.z = cb[d * K + iv.z];
    v.w = cb[d * K + iv.w];
    *reinterpret_cast<float4*>(out + o) = v;
}

extern "C" void kernel_launch(void* const* d_in, const int* in_sizes, int n_in,
                              void* d_out, int out_size, void* d_ws, size_t ws_size,
                              hipStream_t stream) {
    const float* enc = (const float*)d_in[0];
    const float* cb  = (const float*)d_in[1];
    float* out = (float*)d_out;
    char* ws = (char*)d_ws;
    float* ck  = (float*)ws;
    int*   idx = (int*)(ws + 2048);

    vq_prep<<<1, K, 0, stream>>>(cb, ck);
    vq_main<<<NPIX / 64, 256, 0, stream>>>(enc, cb, ck, idx);
    vq_out<<<out_size / 1024, 256, 0, stream>>>(cb, idx, out);
}